// Round 7
// baseline (440.434 us; speedup 1.0000x reference)
//
#include <hip/hip_runtime.h>
#include <math.h>

#define NN 40000
#define NE 600000
#define NG 64
#define DIM_IN 128
#define HH 128
#define HH2 256

using half8 = __attribute__((ext_vector_type(8))) _Float16;
using half4 = __attribute__((ext_vector_type(4))) _Float16;
using h2    = __attribute__((ext_vector_type(2))) _Float16;
using f4    = __attribute__((ext_vector_type(4))) float;

__device__ __forceinline__ int lower_bound_dev(const int* a, int n, int key) {
    int lo = 0, hi = n;
    while (lo < hi) { int mid = (lo + hi) >> 1; if (a[mid] < key) lo = mid + 1; else hi = mid; }
    return lo;
}

// ---------------- weight fp32 -> fp16 conversion (B^T layouts); x stays fp32 ----------------
__global__ void convert_w_kernel(const float* __restrict__ node_w,
                                 const float* __restrict__ lin1_w, const float* __restrict__ lin2_w,
                                 _Float16* __restrict__ nwt,
                                 _Float16* __restrict__ w1t, _Float16* __restrict__ w2t)
{
    int id = blockIdx.x * blockDim.x + threadIdx.x;
    if (id < 16384) { int n = id >> 7, k = id & 127; nwt[id] = (_Float16)node_w[k*128 + n]; return; }
    id -= 16384;
    if (id < 98304) {
        int l = id >> 15, r = id & 32767;
        int n = r >> 7, k = r & 127;
        w1t[id] = (_Float16)lin1_w[l*32768 + k*256 + n];
        return;
    }
    id -= 98304;
    if (id < 98304) {
        int l = id >> 15, r = id & 32767;
        int n = r >> 8, k = r & 255;
        w2t[id] = (_Float16)lin2_w[l*32768 + k*128 + n];
    }
}

// ---------------- CSR build: count+rank, 3-stage scan, no-atomic fill ----------------
__global__ void count_rank_kernel(const int* __restrict__ dst, int* __restrict__ counts,
                                  int* __restrict__ rank) {
    int e = blockIdx.x * blockDim.x + threadIdx.x;
    if (e < NE) rank[e] = atomicAdd(&counts[dst[e]], 1);   // rank write coalesced
}

__global__ __launch_bounds__(1024) void scanA_kernel(const int* __restrict__ counts,
                                                     int* __restrict__ tmp, int* __restrict__ btot) {
    __shared__ int wpre[16];
    int t = threadIdx.x, lane = t & 63, wid = t >> 6;
    int i = blockIdx.x * 1024 + t;
    int v = (i < NN) ? counts[i] : 0;
    int s = v;
    #pragma unroll
    for (int off = 1; off < 64; off <<= 1) {
        int u = __shfl_up(s, off, 64);
        if (lane >= off) s += u;
    }
    if (lane == 63) wpre[wid] = s;
    __syncthreads();
    if (t == 0) {
        int run = 0;
        #pragma unroll
        for (int j = 0; j < 16; ++j) { int xv = wpre[j]; wpre[j] = run; run += xv; }
        btot[blockIdx.x] = run;
    }
    __syncthreads();
    if (i < NN) tmp[i] = s + wpre[wid];
}

__global__ __launch_bounds__(64) void scanB_kernel(const int* __restrict__ btot,
                                                   int* __restrict__ boff, int nb) {
    int t = threadIdx.x;
    int v = (t < nb) ? btot[t] : 0;
    int s = v;
    #pragma unroll
    for (int off = 1; off < 64; off <<= 1) {
        int u = __shfl_up(s, off, 64);
        if (t >= off) s += u;
    }
    if (t < nb) boff[t] = s - v;   // exclusive
}

__global__ __launch_bounds__(1024) void scanC_kernel(const int* __restrict__ tmp,
                                                     const int* __restrict__ boff,
                                                     int* __restrict__ rowp) {
    int i = blockIdx.x * 1024 + threadIdx.x;
    if (i < NN) rowp[i + 1] = tmp[i] + boff[blockIdx.x];
    if (i == 0) rowp[0] = 0;
}

__global__ void fill2_kernel(const int* __restrict__ src, const int* __restrict__ dst,
                             const float* __restrict__ eattr, const int* __restrict__ rowp,
                             const int* __restrict__ rank, int2* __restrict__ rec) {
    int e = blockIdx.x * blockDim.x + threadIdx.x;
    if (e < NE) {
        int pos = rowp[dst[e]] + rank[e];
        rec[pos] = make_int2(src[e], __float_as_int(eattr[e]));   // one 8B scatter, no atomic
    }
}

// ------------- scatter-softmax aggregation v5: R2 pair structure + folded math -------------
__global__ __launch_bounds__(256) void agg_kernel(
    const _Float16* __restrict__ xh,
    const int* __restrict__ row_ptr,
    const int2* __restrict__ rec,
    const float* __restrict__ ew, const float* __restrict__ eb,
    const float* __restrict__ tptr, int layer,
    _Float16* __restrict__ oh)
{
    int d = blockIdx.x * 4 + (threadIdx.x >> 6);
    int lane = threadIdx.x & 63;
    int half = lane >> 5;
    int sl = lane & 31;
    int c0 = 4 * sl;
    float tc2 = tptr[layer] * 1.44269504f;   // t*log2e (t>0)
    float itc = 1.0f / tc2;
    float ewv[4], ebv[4];
    #pragma unroll
    for (int c = 0; c < 4; ++c) { ewv[c] = ew[c0 + c] * tc2; ebv[c] = eb[c0 + c] * tc2; }
    int beg = row_ptr[d], end = row_ptr[d + 1];
    float den[4] = {0.f, 0.f, 0.f, 0.f}, num[4] = {0.f, 0.f, 0.f, 0.f};
    for (int base = beg; base < end; base += 64) {
        int cnt = min(64, end - base);
        int2 mv = rec[base + min(lane, cnt - 1)];   // 64 edges' meta, one coalesced 8B load
        int sv = mv.x;
        float av = __int_as_float(mv.y);
        int pcnt = (cnt + 1) >> 1;                  // pairs of edges
        half4 gA[4], gB[4]; float aA[4], aB[4];
        auto issue = [&](half4 (&g)[4], float (&aa)[4], int p0) {
            #pragma unroll
            for (int u = 0; u < 4; ++u) {
                int je = 2 * (p0 + u) + half;       // <= 63 always (pcnt = ceil(cnt/2))
                int s = __shfl(sv, je, 64);
                aa[u] = __shfl(av, je, 64);
                g[u] = *(const half4*)(xh + ((size_t)s << 7) + c0);
            }
        };
        auto consume = [&](half4 (&g)[4], float (&aa)[4], int p0) {
            #pragma unroll
            for (int u = 0; u < 4; ++u) {
                int je = 2 * (p0 + u) + half;
                if (je < cnt) {   // only tail pair diverges between halves
                    #pragma unroll
                    for (int c = 0; c < 4; ++c) {
                        float p = __fmaf_rn(aa[u], ewv[c], ebv[c]);
                        float r = fmaxf(__fmaf_rn((float)g[u][c], tc2, p), 0.f);  // relu(msg)*tc2
                        float e = exp2f(r);
                        den[c] += e;
                        num[c] = __fmaf_rn(e, r, num[c]);
                    }
                }
            }
        };
        issue(gA, aA, 0);
        for (int p0 = 0; p0 < pcnt; p0 += 8) {
            if (p0 + 4 < pcnt) issue(gB, aB, p0 + 4);
            consume(gA, aA, p0);
            if (p0 + 8 < pcnt) issue(gA, aA, p0 + 8);
            if (p0 + 4 < pcnt) consume(gB, aB, p0 + 4);
        }
    }
    #pragma unroll
    for (int c = 0; c < 4; ++c) {
        den[c] += __shfl_xor(den[c], 32, 64);
        num[c] += __shfl_xor(num[c], 32, 64);
    }
    if (half == 0) {   // 32 lanes x 8B = full 256B row store
        half4 s4 = *(const half4*)(xh + ((size_t)d << 7) + c0);
        half4 ov;
        #pragma unroll
        for (int c = 0; c < 4; ++c) {
            float o = num[c] * itc / fmaxf(den[c], 1e-16f) + 1e-7f + (float)s4[c];
            ov[c] = (_Float16)o;
        }
        *(half4*)(oh + ((size_t)d << 7) + c0) = ov;
    }
}

// ------------- fp16 MFMA GEMM (node linear): A fp32 (converted while staging), Bt fp16 -------------
__global__ __launch_bounds__(256) void gemm_mfma(
    const float* __restrict__ A, const _Float16* __restrict__ Bt,
    const float* __restrict__ bias, _Float16* __restrict__ C,
    int M, int N, int K)
{
    constexpr int LDA = 40;
    __shared__ _Float16 As[64 * LDA];
    __shared__ _Float16 Bs[128 * LDA];
    int t = threadIdx.x;
    int row0 = blockIdx.y * 64;
    int col0 = blockIdx.x * 128;
    int w = t >> 6, lane = t & 63;
    int wm = w & 1, wn = w >> 1;
    int q = lane >> 4, l16 = lane & 15;
    f4 acc[2][4];
    #pragma unroll
    for (int i = 0; i < 2; ++i)
        #pragma unroll
        for (int j = 0; j < 4; ++j)
            acc[i][j] = (f4){0.f, 0.f, 0.f, 0.f};

    for (int k0 = 0; k0 < K; k0 += 32) {
        #pragma unroll
        for (int p = 0; p < 2; ++p) {   // A: 64 rows x 32 fp32 -> fp16 LDS
            int idx = t + p * 256;
            int r = idx >> 3, seg = idx & 7;
            float4 v = *(const float4*)(A + (size_t)(row0 + r) * K + k0 + seg * 4);
            half4 o; o.x = (_Float16)v.x; o.y = (_Float16)v.y; o.z = (_Float16)v.z; o.w = (_Float16)v.w;
            *(half4*)&As[r * LDA + seg * 4] = o;
        }
        #pragma unroll
        for (int i = 0; i < 2; ++i) {
            int idx = t + i * 256;
            int r = idx >> 2, seg = idx & 3;
            *(float4*)&Bs[r * LDA + seg * 8] =
                *(const float4*)(Bt + (size_t)(col0 + r) * K + k0 + seg * 8);
        }
        __syncthreads();
        half8 af[2], bf[4];
        #pragma unroll
        for (int i = 0; i < 2; ++i)
            af[i] = *(const half8*)&As[(wm * 32 + i * 16 + l16) * LDA + q * 8];
        #pragma unroll
        for (int j = 0; j < 4; ++j)
            bf[j] = *(const half8*)&Bs[(wn * 64 + j * 16 + l16) * LDA + q * 8];
        #pragma unroll
        for (int i = 0; i < 2; ++i)
            #pragma unroll
            for (int j = 0; j < 4; ++j)
                acc[i][j] = __builtin_amdgcn_mfma_f32_16x16x32_f16(af[i], bf[j], acc[i][j], 0, 0, 0);
        __syncthreads();
    }
    #pragma unroll
    for (int j = 0; j < 4; ++j) {
        int col = col0 + wn * 64 + j * 16 + l16;
        float bv = bias[col];
        #pragma unroll
        for (int i = 0; i < 2; ++i) {
            int rbase = row0 + wm * 32 + i * 16 + q * 4;
            #pragma unroll
            for (int rg = 0; rg < 4; ++rg)
                C[(size_t)(rbase + rg) * N + col] = (_Float16)(acc[i][j][rg] + bv);
        }
    }
}

// ------------- fused MLP v2: register-fragment GEMMs, 3 barriers, no weight staging -------------
// 512 threads = 8 waves (wm = w&1 row-half, wn = w>>2..: wn = w>>1 in 0..3 col-quarter).
// lin1: A (oh) + w1t fragments direct from global (cache-hot / L2-resident). Only midh in LDS.
// FINAL=1: skip the dead h store.
template<int RES, int FINAL>
__global__ __launch_bounds__(512) void mlp_fused(
    const _Float16* __restrict__ Ain,
    const _Float16* __restrict__ w1t,
    const float* __restrict__ b1,
    const float* __restrict__ g1, const float* __restrict__ bt1,
    const _Float16* __restrict__ w2t,
    const float* __restrict__ b2,
    float* __restrict__ h,
    const float* __restrict__ bg, const float* __restrict__ bb,
    _Float16* __restrict__ xout)
{
    constexpr int LDM = 264;
    __shared__ _Float16 midh[64 * LDM];
    __shared__ float ssum[64][4], ssum2[64][4];
    int t = threadIdx.x;
    int row0 = blockIdx.x * 64;
    int w = t >> 6, lane = t & 63;
    int wm = w & 1, wn = w >> 1;          // wn in 0..3
    int q = lane >> 4, l16 = lane & 15;

    // ---------------- lin1: 64x256 = A(64x128) @ w1t^T, fragments from global ----------------
    f4 acc[2][4];
    #pragma unroll
    for (int i = 0; i < 2; ++i)
        #pragma unroll
        for (int j = 0; j < 4; ++j)
            acc[i][j] = (f4){0.f, 0.f, 0.f, 0.f};
    #pragma unroll
    for (int kk = 0; kk < 4; ++kk) {
        int k0 = kk * 32;
        half8 af[2], bf[4];
        #pragma unroll
        for (int i = 0; i < 2; ++i)
            af[i] = *(const half8*)(Ain + (size_t)(row0 + wm * 32 + i * 16 + l16) * 128 + k0 + q * 8);
        #pragma unroll
        for (int j = 0; j < 4; ++j)
            bf[j] = *(const half8*)(w1t + (size_t)(wn * 64 + j * 16 + l16) * 128 + k0 + q * 8);
        #pragma unroll
        for (int i = 0; i < 2; ++i)
            #pragma unroll
            for (int j = 0; j < 4; ++j)
                acc[i][j] = __builtin_amdgcn_mfma_f32_16x16x32_f16(af[i], bf[j], acc[i][j], 0, 0, 0);
    }

    float b1v[4], g1v[4], bt1v[4];
    #pragma unroll
    for (int j = 0; j < 4; ++j) {
        int col = wn * 64 + j * 16 + l16;
        b1v[j] = b1[col]; g1v[j] = g1[col]; bt1v[j] = bt1[col];
    }
    float vals[2][4][4];
    #pragma unroll
    for (int i = 0; i < 2; ++i)
        #pragma unroll
        for (int j = 0; j < 4; ++j)
            #pragma unroll
            for (int rg = 0; rg < 4; ++rg)
                vals[i][j][rg] = acc[i][j][rg] + b1v[j];
    #pragma unroll
    for (int i = 0; i < 2; ++i) {
        #pragma unroll
        for (int rg = 0; rg < 4; ++rg) {
            float ps = 0.f, ps2 = 0.f;
            #pragma unroll
            for (int j = 0; j < 4; ++j) { float v = vals[i][j][rg]; ps += v; ps2 += v * v; }
            #pragma unroll
            for (int off = 1; off < 16; off <<= 1) {
                ps  += __shfl_xor(ps,  off, 16);
                ps2 += __shfl_xor(ps2, off, 16);
            }
            if (l16 == 0) {
                int row = wm * 32 + i * 16 + q * 4 + rg;
                ssum[row][wn] = ps; ssum2[row][wn] = ps2;
            }
        }
    }
    __syncthreads();                                            // barrier 1
    #pragma unroll
    for (int i = 0; i < 2; ++i) {
        #pragma unroll
        for (int rg = 0; rg < 4; ++rg) {
            int row = wm * 32 + i * 16 + q * 4 + rg;
            float S  = ssum[row][0] + ssum[row][1] + ssum[row][2] + ssum[row][3];
            float S2 = ssum2[row][0] + ssum2[row][1] + ssum2[row][2] + ssum2[row][3];
            float mu = S * (1.0f / 256.0f);
            float var = S2 * (1.0f / 256.0f) - mu * mu;
            float rstd = rsqrtf(var + 1e-5f);
            #pragma unroll
            for (int j = 0; j < 4; ++j) {
                int col = wn * 64 + j * 16 + l16;
                float o = fmaxf((vals[i][j][rg] - mu) * rstd * g1v[j] + bt1v[j], 0.f);
                midh[row * LDM + col] = (_Float16)o;
            }
        }
    }
    __syncthreads();                                            // barrier 2

    // ---------------- lin2: 64x128 = midh(64x256) @ w2t^T, B fragments from global ----------------
    f4 acc2[2][2];
    #pragma unroll
    for (int i = 0; i < 2; ++i)
        #pragma unroll
        for (int j = 0; j < 2; ++j)
            acc2[i][j] = (f4){0.f, 0.f, 0.f, 0.f};
    #pragma unroll
    for (int kk = 0; kk < 8; ++kk) {
        int k0 = kk * 32;
        half8 af2[2], bf2[2];
        #pragma unroll
        for (int i = 0; i < 2; ++i)
            af2[i] = *(const half8*)&midh[(wm * 32 + i * 16 + l16) * LDM + k0 + q * 8];
        #pragma unroll
        for (int j = 0; j < 2; ++j)
            bf2[j] = *(const half8*)(w2t + (size_t)(wn * 32 + j * 16 + l16) * 256 + k0 + q * 8);
        #pragma unroll
        for (int i = 0; i < 2; ++i)
            #pragma unroll
            for (int j = 0; j < 2; ++j)
                acc2[i][j] = __builtin_amdgcn_mfma_f32_16x16x32_f16(af2[i], bf2[j], acc2[i][j], 0, 0, 0);
    }

    float b2v[2], bgv[2], bbv[2];
    #pragma unroll
    for (int j = 0; j < 2; ++j) {
        int col = wn * 32 + j * 16 + l16;
        b2v[j] = b2[col]; bgv[j] = bg[col]; bbv[j] = bb[col];
    }
    float ov[2][2][4];
    #pragma unroll
    for (int i = 0; i < 2; ++i) {
        #pragma unroll
        for (int rg = 0; rg < 4; ++rg) {
            int row = wm * 32 + i * 16 + q * 4 + rg;
            #pragma unroll
            for (int j = 0; j < 2; ++j) {
                int col = wn * 32 + j * 16 + l16;
                float v = acc2[i][j][rg] + b2v[j];
                size_t gidx = (size_t)(row0 + row) * 128 + col;
                if (RES) v += h[gidx];
                if (!FINAL) h[gidx] = v;   // dead after last layer
                ov[i][j][rg] = v;
            }
        }
    }
    #pragma unroll
    for (int i = 0; i < 2; ++i) {
        #pragma unroll
        for (int rg = 0; rg < 4; ++rg) {
            float ps = 0.f, ps2 = 0.f;
            #pragma unroll
            for (int j = 0; j < 2; ++j) { float v = ov[i][j][rg]; ps += v; ps2 += v * v; }
            #pragma unroll
            for (int off = 1; off < 16; off <<= 1) {
                ps  += __shfl_xor(ps,  off, 16);
                ps2 += __shfl_xor(ps2, off, 16);
            }
            if (l16 == 0) {
                int row = wm * 32 + i * 16 + q * 4 + rg;
                ssum[row][wn] = ps; ssum2[row][wn] = ps2;
            }
        }
    }
    __syncthreads();                                            // barrier 3
    #pragma unroll
    for (int i = 0; i < 2; ++i) {
        #pragma unroll
        for (int rg = 0; rg < 4; ++rg) {
            int row = wm * 32 + i * 16 + q * 4 + rg;
            float S  = ssum[row][0] + ssum[row][1] + ssum[row][2] + ssum[row][3];
            float S2 = ssum2[row][0] + ssum2[row][1] + ssum2[row][2] + ssum2[row][3];
            float mu = S * (1.0f / 128.0f);
            float var = S2 * (1.0f / 128.0f) - mu * mu;
            float rstd = rsqrtf(var + 1e-5f);
            #pragma unroll
            for (int j = 0; j < 2; ++j) {
                int col = wn * 32 + j * 16 + l16;
                float o = fmaxf((ov[i][j][rg] - mu) * rstd * bgv[j] + bbv[j], 0.f);
                xout[(size_t)(row0 + row) * 128 + col] = (_Float16)o;
            }
        }
    }
}

// ------------- mean pool over sorted batch (half input): local accumulate, few atomics -------------
__global__ __launch_bounds__(128) void pool_kernel(
    const _Float16* __restrict__ f, const int* __restrict__ batch, float* __restrict__ pooled)
{
    int g = blockIdx.x;
    int chunk = blockIdx.y;
    int c = threadIdx.x;
    int s = lower_bound_dev(batch, NN, g);
    int e = lower_bound_dev(batch, NN, g + 1);
    int len = e - s;
    if (len <= 0) return;
    int nch = gridDim.y;
    int per = (len + nch - 1) / nch;
    int cs = s + chunk * per;
    int ce = min(cs + per, e);
    if (cs >= ce) return;
    float acc = 0.f;
    for (int n = cs; n < ce; ++n) acc += (float)f[(size_t)n * HH + c];
    atomicAdd(&pooled[g * HH + c], acc);
}

// ------------- MLP head (pooled holds per-graph sums; divide by count here) -------------
__global__ __launch_bounds__(128) void head_kernel(
    const float* __restrict__ pooled, const int* __restrict__ batch,
    const float* __restrict__ hw1, const float* __restrict__ hb1,
    const float* __restrict__ hw2, const float* __restrict__ hb2,
    const float* __restrict__ hw3, const float* __restrict__ hb3,
    float* __restrict__ out)
{
    __shared__ float p[HH];
    __shared__ float o1[64];
    __shared__ float o2[32];
    int g = blockIdx.x;
    int t = threadIdx.x;
    int s = lower_bound_dev(batch, NN, g);
    int e = lower_bound_dev(batch, NN, g + 1);
    float cnt = fmaxf((float)(e - s), 1.0f);
    p[t] = pooled[g * HH + t] / cnt;
    __syncthreads();
    if (t < 64) {
        float acc = hb1[t];
        for (int k = 0; k < HH; ++k) acc += p[k] * hw1[k * 64 + t];
        o1[t] = fmaxf(acc, 0.f);
    }
    __syncthreads();
    if (t < 32) {
        float acc = hb2[t];
        for (int k = 0; k < 64; ++k) acc += o1[k] * hw2[k * 32 + t];
        o2[t] = fmaxf(acc, 0.f);
    }
    __syncthreads();
    if (t == 0) {
        float acc = hb3[0];
        for (int k = 0; k < 32; ++k) acc += o2[k] * hw3[k];
        out[g] = acc;
    }
}

extern "C" void kernel_launch(void* const* d_in, const int* in_sizes, int n_in,
                              void* d_out, int out_size, void* d_ws, size_t ws_size,
                              hipStream_t stream)
{
    const float* x      = (const float*)d_in[0];
    const float* eattr  = (const float*)d_in[1];
    const float* node_w = (const float*)d_in[2];
    const float* node_b = (const float*)d_in[3];
    const float* edge_w = (const float*)d_in[4];
    const float* edge_b = (const float*)d_in[5];
    const float* tptr   = (const float*)d_in[6];
    const float* lin1_w = (const float*)d_in[7];
    const float* lin1_b = (const float*)d_in[8];
    const float* ln1_g  = (const float*)d_in[9];
    const float* ln1_bt = (const float*)d_in[10];
    const float* lin2_w = (const float*)d_in[11];
    const float* lin2_b = (const float*)d_in[12];
    const float* blk_g  = (const float*)d_in[13];
    const float* blk_b  = (const float*)d_in[14];
    const float* hw1    = (const float*)d_in[15];
    const float* hb1    = (const float*)d_in[16];
    const float* hw2    = (const float*)d_in[17];
    const float* hb2    = (const float*)d_in[18];
    const float* hw3    = (const float*)d_in[19];
    const float* hb3    = (const float*)d_in[20];
    const int*   eidx   = (const int*)d_in[21];
    const int*   batch  = (const int*)d_in[22];
    const int* src = eidx;
    const int* dst = eidx + NE;
    float* out = (float*)d_out;

    char* ws = (char*)d_ws;
    size_t off = 0;
    auto carve = [&](size_t bytes) -> char* {
        char* p = ws + off;
        off = (off + bytes + 255) & ~(size_t)255;
        return p;
    };
    float*    h      = (float*)carve((size_t)NN * HH * 4);
    _Float16* xnh    = (_Float16*)carve((size_t)NN * HH * 2);
    _Float16* oh     = (_Float16*)carve((size_t)NN * HH * 2);
    _Float16* rh     = (_Float16*)carve((size_t)NN * HH * 2);
    _Float16* nwt    = (_Float16*)carve((size_t)16384 * 2);
    _Float16* w1t    = (_Float16*)carve((size_t)98304 * 2);
    _Float16* w2t    = (_Float16*)carve((size_t)98304 * 2);
    int*      counts = (int*)carve((size_t)NN * 4);
    int*      rank   = (int*)carve((size_t)NE * 4);
    int*      tmp    = (int*)carve((size_t)NN * 4);
    int*      btot   = (int*)carve((size_t)64 * 4);
    int*      boff   = (int*)carve((size_t)64 * 4);
    int*      rowp   = (int*)carve((size_t)(NN + 1) * 4);
    int2*     rec    = (int2*)carve((size_t)NE * 8);
    float*    pooled = (float*)carve((size_t)NG * HH * 4);

    hipMemsetAsync(counts, 0, (size_t)NN * 4, stream);
    hipMemsetAsync(pooled, 0, (size_t)NG * HH * 4, stream);

    {
        int total = 16384 + 98304 + 98304;   // 832 blocks
        convert_w_kernel<<<(total + 255) / 256, 256, 0, stream>>>(
            node_w, lin1_w, lin2_w, nwt, w1t, w2t);
    }
    const int NB = (NN + 1023) / 1024;   // 40
    count_rank_kernel<<<(NE + 255) / 256, 256, 0, stream>>>(dst, counts, rank);
    scanA_kernel<<<NB, 1024, 0, stream>>>(counts, tmp, btot);
    scanB_kernel<<<1, 64, 0, stream>>>(btot, boff, NB);
    scanC_kernel<<<NB, 1024, 0, stream>>>(tmp, boff, rowp);
    fill2_kernel<<<(NE + 255) / 256, 256, 0, stream>>>(src, dst, eattr, rowp, rank, rec);

    // node linear: xnh = half(x @ node_w + node_b)  (reads fp32 x directly)
    gemm_mfma<<<dim3(1, NN / 64), 256, 0, stream>>>(x, nwt, node_b, xnh, NN, HH, DIM_IN);

    // layer 0 (no residual; post-LN uses blk[1])
    agg_kernel<<<NN / 4, 256, 0, stream>>>(xnh, rowp, rec, edge_w, edge_b, tptr, 0, oh);
    mlp_fused<0, 0><<<NN / 64, 512, 0, stream>>>(
        oh, w1t, lin1_b, ln1_g, ln1_bt, w2t, lin2_b,
        h, blk_g + 1 * HH, blk_b + 1 * HH, xnh);
    // layer 1 (residual; post-LN uses blk[2])
    agg_kernel<<<NN / 4, 256, 0, stream>>>(xnh, rowp, rec, edge_w, edge_b, tptr, 1, oh);
    mlp_fused<1, 0><<<NN / 64, 512, 0, stream>>>(
        oh, w1t + 32768, lin1_b + HH2, ln1_g + HH2, ln1_bt + HH2, w2t + 32768, lin2_b + HH,
        h, blk_g + 2 * HH, blk_b + 2 * HH, xnh);
    // layer 2 (residual; final LN uses blk[0] -> rh; dead h store skipped)
    agg_kernel<<<NN / 4, 256, 0, stream>>>(xnh, rowp, rec, edge_w, edge_b, tptr, 2, oh);
    mlp_fused<1, 1><<<NN / 64, 512, 0, stream>>>(
        oh, w1t + 2 * 32768, lin1_b + 2 * HH2, ln1_g + 2 * HH2, ln1_bt + 2 * HH2,
        w2t + 2 * 32768, lin2_b + 2 * HH,
        h, blk_g, blk_b, rh);

    pool_kernel<<<dim3(NG, 8), 128, 0, stream>>>(rh, batch, pooled);
    head_kernel<<<NG, 128, 0, stream>>>(pooled, batch, hw1, hb1, hw2, hb2, hw3, hb3, out);
}

// Round 8
// 399.139 us; speedup vs baseline: 1.1035x; 1.1035x over previous
//
#include <hip/hip_runtime.h>
#include <math.h>

#define NN 40000
#define NE 600000
#define NG 64
#define DIM_IN 128
#define HH 128
#define HH2 256

using half8 = __attribute__((ext_vector_type(8))) _Float16;
using half4 = __attribute__((ext_vector_type(4))) _Float16;
using h2    = __attribute__((ext_vector_type(2))) _Float16;
using f4    = __attribute__((ext_vector_type(4))) float;

__device__ __forceinline__ int lower_bound_dev(const int* a, int n, int key) {
    int lo = 0, hi = n;
    while (lo < hi) { int mid = (lo + hi) >> 1; if (a[mid] < key) lo = mid + 1; else hi = mid; }
    return lo;
}

// ---------------- weight fp32 -> fp16 conversion (B^T layouts); x stays fp32 ----------------
__global__ void convert_w_kernel(const float* __restrict__ node_w,
                                 const float* __restrict__ lin1_w, const float* __restrict__ lin2_w,
                                 _Float16* __restrict__ nwt,
                                 _Float16* __restrict__ w1t, _Float16* __restrict__ w2t)
{
    int id = blockIdx.x * blockDim.x + threadIdx.x;
    if (id < 16384) { int n = id >> 7, k = id & 127; nwt[id] = (_Float16)node_w[k*128 + n]; return; }
    id -= 16384;
    if (id < 98304) {
        int l = id >> 15, r = id & 32767;
        int n = r >> 7, k = r & 127;
        w1t[id] = (_Float16)lin1_w[l*32768 + k*256 + n];
        return;
    }
    id -= 98304;
    if (id < 98304) {
        int l = id >> 15, r = id & 32767;
        int n = r >> 8, k = r & 255;
        w2t[id] = (_Float16)lin2_w[l*32768 + k*128 + n];
    }
}

// ---------------- CSR build: count+rank, 3-stage scan, no-atomic fill ----------------
__global__ void count_rank_kernel(const int* __restrict__ dst, int* __restrict__ counts,
                                  int* __restrict__ rank) {
    int e = blockIdx.x * blockDim.x + threadIdx.x;
    if (e < NE) rank[e] = atomicAdd(&counts[dst[e]], 1);   // rank write coalesced
}

__global__ __launch_bounds__(1024) void scanA_kernel(const int* __restrict__ counts,
                                                     int* __restrict__ tmp, int* __restrict__ btot) {
    __shared__ int wpre[16];
    int t = threadIdx.x, lane = t & 63, wid = t >> 6;
    int i = blockIdx.x * 1024 + t;
    int v = (i < NN) ? counts[i] : 0;
    int s = v;
    #pragma unroll
    for (int off = 1; off < 64; off <<= 1) {
        int u = __shfl_up(s, off, 64);
        if (lane >= off) s += u;
    }
    if (lane == 63) wpre[wid] = s;
    __syncthreads();
    if (t == 0) {
        int run = 0;
        #pragma unroll
        for (int j = 0; j < 16; ++j) { int xv = wpre[j]; wpre[j] = run; run += xv; }
        btot[blockIdx.x] = run;
    }
    __syncthreads();
    if (i < NN) tmp[i] = s + wpre[wid];
}

__global__ __launch_bounds__(64) void scanB_kernel(const int* __restrict__ btot,
                                                   int* __restrict__ boff, int nb) {
    int t = threadIdx.x;
    int v = (t < nb) ? btot[t] : 0;
    int s = v;
    #pragma unroll
    for (int off = 1; off < 64; off <<= 1) {
        int u = __shfl_up(s, off, 64);
        if (t >= off) s += u;
    }
    if (t < nb) boff[t] = s - v;   // exclusive
}

__global__ __launch_bounds__(1024) void scanC_kernel(const int* __restrict__ tmp,
                                                     const int* __restrict__ boff,
                                                     int* __restrict__ rowp) {
    int i = blockIdx.x * 1024 + threadIdx.x;
    if (i < NN) rowp[i + 1] = tmp[i] + boff[blockIdx.x];
    if (i == 0) rowp[0] = 0;
}

__global__ void fill2_kernel(const int* __restrict__ src, const int* __restrict__ dst,
                             const float* __restrict__ eattr, const int* __restrict__ rowp,
                             const int* __restrict__ rank, int2* __restrict__ rec) {
    int e = blockIdx.x * blockDim.x + threadIdx.x;
    if (e < NE) {
        int pos = rowp[dst[e]] + rank[e];
        rec[pos] = make_int2(src[e], __float_as_int(eattr[e]));   // one 8B scatter, no atomic
    }
}

// ------------- scatter-softmax aggregation v5: R2 pair structure + folded math -------------
__global__ __launch_bounds__(256) void agg_kernel(
    const _Float16* __restrict__ xh,
    const int* __restrict__ row_ptr,
    const int2* __restrict__ rec,
    const float* __restrict__ ew, const float* __restrict__ eb,
    const float* __restrict__ tptr, int layer,
    _Float16* __restrict__ oh)
{
    int d = blockIdx.x * 4 + (threadIdx.x >> 6);
    int lane = threadIdx.x & 63;
    int half = lane >> 5;
    int sl = lane & 31;
    int c0 = 4 * sl;
    float tc2 = tptr[layer] * 1.44269504f;   // t*log2e (t>0)
    float itc = 1.0f / tc2;
    float ewv[4], ebv[4];
    #pragma unroll
    for (int c = 0; c < 4; ++c) { ewv[c] = ew[c0 + c] * tc2; ebv[c] = eb[c0 + c] * tc2; }
    int beg = row_ptr[d], end = row_ptr[d + 1];
    float den[4] = {0.f, 0.f, 0.f, 0.f}, num[4] = {0.f, 0.f, 0.f, 0.f};
    for (int base = beg; base < end; base += 64) {
        int cnt = min(64, end - base);
        int2 mv = rec[base + min(lane, cnt - 1)];   // 64 edges' meta, one coalesced 8B load
        int sv = mv.x;
        float av = __int_as_float(mv.y);
        int pcnt = (cnt + 1) >> 1;                  // pairs of edges
        half4 gA[4], gB[4]; float aA[4], aB[4];
        auto issue = [&](half4 (&g)[4], float (&aa)[4], int p0) {
            #pragma unroll
            for (int u = 0; u < 4; ++u) {
                int je = 2 * (p0 + u) + half;       // <= 63 always (pcnt = ceil(cnt/2))
                int s = __shfl(sv, je, 64);
                aa[u] = __shfl(av, je, 64);
                g[u] = *(const half4*)(xh + ((size_t)s << 7) + c0);
            }
        };
        auto consume = [&](half4 (&g)[4], float (&aa)[4], int p0) {
            #pragma unroll
            for (int u = 0; u < 4; ++u) {
                int je = 2 * (p0 + u) + half;
                if (je < cnt) {   // only tail pair diverges between halves
                    #pragma unroll
                    for (int c = 0; c < 4; ++c) {
                        float p = __fmaf_rn(aa[u], ewv[c], ebv[c]);
                        float r = fmaxf(__fmaf_rn((float)g[u][c], tc2, p), 0.f);  // relu(msg)*tc2
                        float e = exp2f(r);
                        den[c] += e;
                        num[c] = __fmaf_rn(e, r, num[c]);
                    }
                }
            }
        };
        issue(gA, aA, 0);
        for (int p0 = 0; p0 < pcnt; p0 += 8) {
            if (p0 + 4 < pcnt) issue(gB, aB, p0 + 4);
            consume(gA, aA, p0);
            if (p0 + 8 < pcnt) issue(gA, aA, p0 + 8);
            if (p0 + 4 < pcnt) consume(gB, aB, p0 + 4);
        }
    }
    #pragma unroll
    for (int c = 0; c < 4; ++c) {
        den[c] += __shfl_xor(den[c], 32, 64);
        num[c] += __shfl_xor(num[c], 32, 64);
    }
    if (half == 0) {   // 32 lanes x 8B = full 256B row store
        half4 s4 = *(const half4*)(xh + ((size_t)d << 7) + c0);
        half4 ov;
        #pragma unroll
        for (int c = 0; c < 4; ++c) {
            float o = num[c] * itc / fmaxf(den[c], 1e-16f) + 1e-7f + (float)s4[c];
            ov[c] = (_Float16)o;
        }
        *(half4*)(oh + ((size_t)d << 7) + c0) = ov;
    }
}

// ------------- fp16 MFMA GEMM (node linear): A fp32 (converted while staging), Bt fp16 -------------
__global__ __launch_bounds__(256) void gemm_mfma(
    const float* __restrict__ A, const _Float16* __restrict__ Bt,
    const float* __restrict__ bias, _Float16* __restrict__ C,
    int M, int N, int K)
{
    constexpr int LDA = 40;
    __shared__ _Float16 As[64 * LDA];
    __shared__ _Float16 Bs[128 * LDA];
    int t = threadIdx.x;
    int row0 = blockIdx.y * 64;
    int col0 = blockIdx.x * 128;
    int w = t >> 6, lane = t & 63;
    int wm = w & 1, wn = w >> 1;
    int q = lane >> 4, l16 = lane & 15;
    f4 acc[2][4];
    #pragma unroll
    for (int i = 0; i < 2; ++i)
        #pragma unroll
        for (int j = 0; j < 4; ++j)
            acc[i][j] = (f4){0.f, 0.f, 0.f, 0.f};

    for (int k0 = 0; k0 < K; k0 += 32) {
        #pragma unroll
        for (int p = 0; p < 2; ++p) {   // A: 64 rows x 32 fp32 -> fp16 LDS
            int idx = t + p * 256;
            int r = idx >> 3, seg = idx & 7;
            float4 v = *(const float4*)(A + (size_t)(row0 + r) * K + k0 + seg * 4);
            half4 o; o.x = (_Float16)v.x; o.y = (_Float16)v.y; o.z = (_Float16)v.z; o.w = (_Float16)v.w;
            *(half4*)&As[r * LDA + seg * 4] = o;
        }
        #pragma unroll
        for (int i = 0; i < 2; ++i) {
            int idx = t + i * 256;
            int r = idx >> 2, seg = idx & 3;
            *(float4*)&Bs[r * LDA + seg * 8] =
                *(const float4*)(Bt + (size_t)(col0 + r) * K + k0 + seg * 8);
        }
        __syncthreads();
        half8 af[2], bf[4];
        #pragma unroll
        for (int i = 0; i < 2; ++i)
            af[i] = *(const half8*)&As[(wm * 32 + i * 16 + l16) * LDA + q * 8];
        #pragma unroll
        for (int j = 0; j < 4; ++j)
            bf[j] = *(const half8*)&Bs[(wn * 64 + j * 16 + l16) * LDA + q * 8];
        #pragma unroll
        for (int i = 0; i < 2; ++i)
            #pragma unroll
            for (int j = 0; j < 4; ++j)
                acc[i][j] = __builtin_amdgcn_mfma_f32_16x16x32_f16(af[i], bf[j], acc[i][j], 0, 0, 0);
        __syncthreads();
    }
    #pragma unroll
    for (int j = 0; j < 4; ++j) {
        int col = col0 + wn * 64 + j * 16 + l16;
        float bv = bias[col];
        #pragma unroll
        for (int i = 0; i < 2; ++i) {
            int rbase = row0 + wm * 32 + i * 16 + q * 4;
            #pragma unroll
            for (int rg = 0; rg < 4; ++rg)
                C[(size_t)(rbase + rg) * N + col] = (_Float16)(acc[i][j][rg] + bv);
        }
    }
}

// ------------- fused: lin1 -> LN1 -> ReLU -> lin2 (+bias) [+res] -> h; blockLN -> ReLU -> xout -------------
// Staged-LDS version (measured-best structure). FINAL=1: skip the dead h store.
template<int RES, int FINAL>
__global__ __launch_bounds__(256) void mlp_fused(
    const _Float16* __restrict__ Ain,
    const _Float16* __restrict__ w1t,
    const float* __restrict__ b1,
    const float* __restrict__ g1, const float* __restrict__ bt1,
    const _Float16* __restrict__ w2t,
    const float* __restrict__ b2,
    float* __restrict__ h,
    const float* __restrict__ bg, const float* __restrict__ bb,
    _Float16* __restrict__ xout)
{
    constexpr int LDA = 136;
    constexpr int LDB = 40;
    constexpr int LDM = 264;
    __shared__ _Float16 As[64 * LDA];
    __shared__ _Float16 Bs[256 * LDB];
    __shared__ _Float16 midh[64 * LDM];
    __shared__ float ssum[64][2], ssum2[64][2];
    int t = threadIdx.x;
    int row0 = blockIdx.x * 64;
    int w = t >> 6, lane = t & 63;
    int wm = w & 1, wn = w >> 1;
    int q = lane >> 4, l16 = lane & 15;

    #pragma unroll
    for (int p = 0; p < 4; ++p) {
        int idx = t + p * 256;
        int r = idx >> 4, seg = idx & 15;
        *(float4*)&As[r * LDA + seg * 8] =
            *(const float4*)(Ain + (size_t)(row0 + r) * 128 + seg * 8);
    }

    f4 acc[2][8];
    #pragma unroll
    for (int i = 0; i < 2; ++i)
        #pragma unroll
        for (int j = 0; j < 8; ++j)
            acc[i][j] = (f4){0.f, 0.f, 0.f, 0.f};
    for (int k0 = 0; k0 < 128; k0 += 32) {
        #pragma unroll
        for (int p = 0; p < 4; ++p) {
            int idx = t + p * 256;
            int r = idx >> 2, seg = idx & 3;
            *(float4*)&Bs[r * LDB + seg * 8] =
                *(const float4*)(w1t + (size_t)r * 128 + k0 + seg * 8);
        }
        __syncthreads();
        half8 af[2], bf[8];
        #pragma unroll
        for (int i = 0; i < 2; ++i)
            af[i] = *(const half8*)&As[(wm * 32 + i * 16 + l16) * LDA + k0 + q * 8];
        #pragma unroll
        for (int j = 0; j < 8; ++j)
            bf[j] = *(const half8*)&Bs[(wn * 128 + j * 16 + l16) * LDB + q * 8];
        #pragma unroll
        for (int i = 0; i < 2; ++i)
            #pragma unroll
            for (int j = 0; j < 8; ++j)
                acc[i][j] = __builtin_amdgcn_mfma_f32_16x16x32_f16(af[i], bf[j], acc[i][j], 0, 0, 0);
        __syncthreads();
    }

    float b1v[8], g1v[8], bt1v[8];
    #pragma unroll
    for (int j = 0; j < 8; ++j) {
        int col = wn * 128 + j * 16 + l16;
        b1v[j] = b1[col]; g1v[j] = g1[col]; bt1v[j] = bt1[col];
    }
    float vals[2][8][4];
    #pragma unroll
    for (int i = 0; i < 2; ++i)
        #pragma unroll
        for (int j = 0; j < 8; ++j)
            #pragma unroll
            for (int rg = 0; rg < 4; ++rg)
                vals[i][j][rg] = acc[i][j][rg] + b1v[j];
    #pragma unroll
    for (int i = 0; i < 2; ++i) {
        #pragma unroll
        for (int rg = 0; rg < 4; ++rg) {
            float ps = 0.f, ps2 = 0.f;
            #pragma unroll
            for (int j = 0; j < 8; ++j) { float v = vals[i][j][rg]; ps += v; ps2 += v * v; }
            #pragma unroll
            for (int off = 1; off < 16; off <<= 1) {
                ps  += __shfl_xor(ps,  off, 16);
                ps2 += __shfl_xor(ps2, off, 16);
            }
            if (l16 == 0) {
                int row = wm * 32 + i * 16 + q * 4 + rg;
                ssum[row][wn] = ps; ssum2[row][wn] = ps2;
            }
        }
    }
    __syncthreads();
    #pragma unroll
    for (int i = 0; i < 2; ++i) {
        #pragma unroll
        for (int rg = 0; rg < 4; ++rg) {
            int row = wm * 32 + i * 16 + q * 4 + rg;
            float S = ssum[row][0] + ssum[row][1];
            float S2 = ssum2[row][0] + ssum2[row][1];
            float mu = S * (1.0f / 256.0f);
            float var = S2 * (1.0f / 256.0f) - mu * mu;
            float rstd = rsqrtf(var + 1e-5f);
            #pragma unroll
            for (int j = 0; j < 8; ++j) {
                int col = wn * 128 + j * 16 + l16;
                float o = fmaxf((vals[i][j][rg] - mu) * rstd * g1v[j] + bt1v[j], 0.f);
                midh[row * LDM + col] = (_Float16)o;
            }
        }
    }
    __syncthreads();

    f4 acc2[2][4];
    #pragma unroll
    for (int i = 0; i < 2; ++i)
        #pragma unroll
        for (int j = 0; j < 4; ++j)
            acc2[i][j] = (f4){0.f, 0.f, 0.f, 0.f};
    for (int k0 = 0; k0 < 256; k0 += 32) {
        #pragma unroll
        for (int p = 0; p < 2; ++p) {
            int idx = t + p * 256;
            int r = idx >> 2, seg = idx & 3;
            *(float4*)&Bs[r * LDB + seg * 8] =
                *(const float4*)(w2t + (size_t)r * 256 + k0 + seg * 8);
        }
        __syncthreads();
        half8 af2[2], bf2[4];
        #pragma unroll
        for (int i = 0; i < 2; ++i)
            af2[i] = *(const half8*)&midh[(wm * 32 + i * 16 + l16) * LDM + k0 + q * 8];
        #pragma unroll
        for (int j = 0; j < 4; ++j)
            bf2[j] = *(const half8*)&Bs[(wn * 64 + j * 16 + l16) * LDB + q * 8];
        #pragma unroll
        for (int i = 0; i < 2; ++i)
            #pragma unroll
            for (int j = 0; j < 4; ++j)
                acc2[i][j] = __builtin_amdgcn_mfma_f32_16x16x32_f16(af2[i], bf2[j], acc2[i][j], 0, 0, 0);
        __syncthreads();
    }

    float b2v[4], bgv[4], bbv[4];
    #pragma unroll
    for (int j = 0; j < 4; ++j) {
        int col = wn * 64 + j * 16 + l16;
        b2v[j] = b2[col]; bgv[j] = bg[col]; bbv[j] = bb[col];
    }
    float ov[2][4][4];
    #pragma unroll
    for (int i = 0; i < 2; ++i) {
        #pragma unroll
        for (int rg = 0; rg < 4; ++rg) {
            int row = wm * 32 + i * 16 + q * 4 + rg;
            #pragma unroll
            for (int j = 0; j < 4; ++j) {
                int col = wn * 64 + j * 16 + l16;
                float v = acc2[i][j][rg] + b2v[j];
                size_t gidx = (size_t)(row0 + row) * 128 + col;
                if (RES) v += h[gidx];
                if (!FINAL) h[gidx] = v;   // dead after last layer
                ov[i][j][rg] = v;
            }
        }
    }
    #pragma unroll
    for (int i = 0; i < 2; ++i) {
        #pragma unroll
        for (int rg = 0; rg < 4; ++rg) {
            float ps = 0.f, ps2 = 0.f;
            #pragma unroll
            for (int j = 0; j < 4; ++j) { float v = ov[i][j][rg]; ps += v; ps2 += v * v; }
            #pragma unroll
            for (int off = 1; off < 16; off <<= 1) {
                ps  += __shfl_xor(ps,  off, 16);
                ps2 += __shfl_xor(ps2, off, 16);
            }
            if (l16 == 0) {
                int row = wm * 32 + i * 16 + q * 4 + rg;
                ssum[row][wn] = ps; ssum2[row][wn] = ps2;
            }
        }
    }
    __syncthreads();
    #pragma unroll
    for (int i = 0; i < 2; ++i) {
        #pragma unroll
        for (int rg = 0; rg < 4; ++rg) {
            int row = wm * 32 + i * 16 + q * 4 + rg;
            float S = ssum[row][0] + ssum[row][1];
            float S2 = ssum2[row][0] + ssum2[row][1];
            float mu = S * (1.0f / 128.0f);
            float var = S2 * (1.0f / 128.0f) - mu * mu;
            float rstd = rsqrtf(var + 1e-5f);
            #pragma unroll
            for (int j = 0; j < 4; ++j) {
                int col = wn * 64 + j * 16 + l16;
                float o = fmaxf((ov[i][j][rg] - mu) * rstd * bgv[j] + bbv[j], 0.f);
                xout[(size_t)(row0 + row) * 128 + col] = (_Float16)o;
            }
        }
    }
}

// ------------- mean pool over sorted batch (half input): local accumulate, few atomics -------------
__global__ __launch_bounds__(128) void pool_kernel(
    const _Float16* __restrict__ f, const int* __restrict__ batch, float* __restrict__ pooled)
{
    int g = blockIdx.x;
    int chunk = blockIdx.y;
    int c = threadIdx.x;
    int s = lower_bound_dev(batch, NN, g);
    int e = lower_bound_dev(batch, NN, g + 1);
    int len = e - s;
    if (len <= 0) return;
    int nch = gridDim.y;
    int per = (len + nch - 1) / nch;
    int cs = s + chunk * per;
    int ce = min(cs + per, e);
    if (cs >= ce) return;
    float acc = 0.f;
    for (int n = cs; n < ce; ++n) acc += (float)f[(size_t)n * HH + c];
    atomicAdd(&pooled[g * HH + c], acc);
}

// ------------- MLP head (pooled holds per-graph sums; divide by count here) -------------
__global__ __launch_bounds__(128) void head_kernel(
    const float* __restrict__ pooled, const int* __restrict__ batch,
    const float* __restrict__ hw1, const float* __restrict__ hb1,
    const float* __restrict__ hw2, const float* __restrict__ hb2,
    const float* __restrict__ hw3, const float* __restrict__ hb3,
    float* __restrict__ out)
{
    __shared__ float p[HH];
    __shared__ float o1[64];
    __shared__ float o2[32];
    int g = blockIdx.x;
    int t = threadIdx.x;
    int s = lower_bound_dev(batch, NN, g);
    int e = lower_bound_dev(batch, NN, g + 1);
    float cnt = fmaxf((float)(e - s), 1.0f);
    p[t] = pooled[g * HH + t] / cnt;
    __syncthreads();
    if (t < 64) {
        float acc = hb1[t];
        for (int k = 0; k < HH; ++k) acc += p[k] * hw1[k * 64 + t];
        o1[t] = fmaxf(acc, 0.f);
    }
    __syncthreads();
    if (t < 32) {
        float acc = hb2[t];
        for (int k = 0; k < 64; ++k) acc += o1[k] * hw2[k * 32 + t];
        o2[t] = fmaxf(acc, 0.f);
    }
    __syncthreads();
    if (t == 0) {
        float acc = hb3[0];
        for (int k = 0; k < 32; ++k) acc += o2[k] * hw3[k];
        out[g] = acc;
    }
}

extern "C" void kernel_launch(void* const* d_in, const int* in_sizes, int n_in,
                              void* d_out, int out_size, void* d_ws, size_t ws_size,
                              hipStream_t stream)
{
    const float* x      = (const float*)d_in[0];
    const float* eattr  = (const float*)d_in[1];
    const float* node_w = (const float*)d_in[2];
    const float* node_b = (const float*)d_in[3];
    const float* edge_w = (const float*)d_in[4];
    const float* edge_b = (const float*)d_in[5];
    const float* tptr   = (const float*)d_in[6];
    const float* lin1_w = (const float*)d_in[7];
    const float* lin1_b = (const float*)d_in[8];
    const float* ln1_g  = (const float*)d_in[9];
    const float* ln1_bt = (const float*)d_in[10];
    const float* lin2_w = (const float*)d_in[11];
    const float* lin2_b = (const float*)d_in[12];
    const float* blk_g  = (const float*)d_in[13];
    const float* blk_b  = (const float*)d_in[14];
    const float* hw1    = (const float*)d_in[15];
    const float* hb1    = (const float*)d_in[16];
    const float* hw2    = (const float*)d_in[17];
    const float* hb2    = (const float*)d_in[18];
    const float* hw3    = (const float*)d_in[19];
    const float* hb3    = (const float*)d_in[20];
    const int*   eidx   = (const int*)d_in[21];
    const int*   batch  = (const int*)d_in[22];
    const int* src = eidx;
    const int* dst = eidx + NE;
    float* out = (float*)d_out;

    char* ws = (char*)d_ws;
    size_t off = 0;
    auto carve = [&](size_t bytes) -> char* {
        char* p = ws + off;
        off = (off + bytes + 255) & ~(size_t)255;
        return p;
    };
    float*    h      = (float*)carve((size_t)NN * HH * 4);
    _Float16* xnh    = (_Float16*)carve((size_t)NN * HH * 2);
    _Float16* oh     = (_Float16*)carve((size_t)NN * HH * 2);
    _Float16* rh     = (_Float16*)carve((size_t)NN * HH * 2);
    _Float16* nwt    = (_Float16*)carve((size_t)16384 * 2);
    _Float16* w1t    = (_Float16*)carve((size_t)98304 * 2);
    _Float16* w2t    = (_Float16*)carve((size_t)98304 * 2);
    int*      counts = (int*)carve((size_t)NN * 4);
    int*      rank   = (int*)carve((size_t)NE * 4);
    int*      tmp    = (int*)carve((size_t)NN * 4);
    int*      btot   = (int*)carve((size_t)64 * 4);
    int*      boff   = (int*)carve((size_t)64 * 4);
    int*      rowp   = (int*)carve((size_t)(NN + 1) * 4);
    int2*     rec    = (int2*)carve((size_t)NE * 8);
    float*    pooled = (float*)carve((size_t)NG * HH * 4);

    hipMemsetAsync(counts, 0, (size_t)NN * 4, stream);
    hipMemsetAsync(pooled, 0, (size_t)NG * HH * 4, stream);

    {
        int total = 16384 + 98304 + 98304;   // 832 blocks
        convert_w_kernel<<<(total + 255) / 256, 256, 0, stream>>>(
            node_w, lin1_w, lin2_w, nwt, w1t, w2t);
    }
    const int NB = (NN + 1023) / 1024;   // 40
    count_rank_kernel<<<(NE + 255) / 256, 256, 0, stream>>>(dst, counts, rank);
    scanA_kernel<<<NB, 1024, 0, stream>>>(counts, tmp, btot);
    scanB_kernel<<<1, 64, 0, stream>>>(btot, boff, NB);
    scanC_kernel<<<NB, 1024, 0, stream>>>(tmp, boff, rowp);
    fill2_kernel<<<(NE + 255) / 256, 256, 0, stream>>>(src, dst, eattr, rowp, rank, rec);

    // node linear: xnh = half(x @ node_w + node_b)  (reads fp32 x directly)
    gemm_mfma<<<dim3(1, NN / 64), 256, 0, stream>>>(x, nwt, node_b, xnh, NN, HH, DIM_IN);

    // layer 0 (no residual; post-LN uses blk[1])
    agg_kernel<<<NN / 4, 256, 0, stream>>>(xnh, rowp, rec, edge_w, edge_b, tptr, 0, oh);
    mlp_fused<0, 0><<<NN / 64, 256, 0, stream>>>(
        oh, w1t, lin1_b, ln1_g, ln1_bt, w2t, lin2_b,
        h, blk_g + 1 * HH, blk_b + 1 * HH, xnh);
    // layer 1 (residual; post-LN uses blk[2])
    agg_kernel<<<NN / 4, 256, 0, stream>>>(xnh, rowp, rec, edge_w, edge_b, tptr, 1, oh);
    mlp_fused<1, 0><<<NN / 64, 256, 0, stream>>>(
        oh, w1t + 32768, lin1_b + HH2, ln1_g + HH2, ln1_bt + HH2, w2t + 32768, lin2_b + HH,
        h, blk_g + 2 * HH, blk_b + 2 * HH, xnh);
    // layer 2 (residual; final LN uses blk[0] -> rh; dead h store skipped)
    agg_kernel<<<NN / 4, 256, 0, stream>>>(xnh, rowp, rec, edge_w, edge_b, tptr, 2, oh);
    mlp_fused<1, 1><<<NN / 64, 256, 0, stream>>>(
        oh, w1t + 2 * 32768, lin1_b + 2 * HH2, ln1_g + 2 * HH2, ln1_bt + 2 * HH2,
        w2t + 2 * 32768, lin2_b + 2 * HH,
        h, blk_g, blk_b, rh);

    pool_kernel<<<dim3(NG, 8), 128, 0, stream>>>(rh, batch, pooled);
    head_kernel<<<NG, 128, 0, stream>>>(pooled, batch, hw1, hb1, hw2, hb2, hw3, hb3, out);
}

// Round 9
// 381.817 us; speedup vs baseline: 1.1535x; 1.0454x over previous
//
#include <hip/hip_runtime.h>
#include <math.h>

#define NN 40000
#define NE 600000
#define NG 64
#define DIM_IN 128
#define HH 128
#define HH2 256

using half8 = __attribute__((ext_vector_type(8))) _Float16;
using half4 = __attribute__((ext_vector_type(4))) _Float16;
using h2    = __attribute__((ext_vector_type(2))) _Float16;
using f4    = __attribute__((ext_vector_type(4))) float;

__device__ __forceinline__ int lower_bound_dev(const int* a, int n, int key) {
    int lo = 0, hi = n;
    while (lo < hi) { int mid = (lo + hi) >> 1; if (a[mid] < key) lo = mid + 1; else hi = mid; }
    return lo;
}

// ---------------- weight fp32 -> fp16 conversion (B^T layouts); x stays fp32 ----------------
__global__ void convert_w_kernel(const float* __restrict__ node_w,
                                 const float* __restrict__ lin1_w, const float* __restrict__ lin2_w,
                                 _Float16* __restrict__ nwt,
                                 _Float16* __restrict__ w1t, _Float16* __restrict__ w2t)
{
    int id = blockIdx.x * blockDim.x + threadIdx.x;
    if (id < 16384) { int n = id >> 7, k = id & 127; nwt[id] = (_Float16)node_w[k*128 + n]; return; }
    id -= 16384;
    if (id < 98304) {
        int l = id >> 15, r = id & 32767;
        int n = r >> 7, k = r & 127;
        w1t[id] = (_Float16)lin1_w[l*32768 + k*256 + n];
        return;
    }
    id -= 98304;
    if (id < 98304) {
        int l = id >> 15, r = id & 32767;
        int n = r >> 8, k = r & 255;
        w2t[id] = (_Float16)lin2_w[l*32768 + k*128 + n];
    }
}

// ---------------- CSR build: count+rank, 3-stage scan, no-atomic fill ----------------
__global__ void count_rank_kernel(const int* __restrict__ dst, int* __restrict__ counts,
                                  int* __restrict__ rank) {
    int e = blockIdx.x * blockDim.x + threadIdx.x;
    if (e < NE) rank[e] = atomicAdd(&counts[dst[e]], 1);   // rank write coalesced
}

__global__ __launch_bounds__(1024) void scanA_kernel(const int* __restrict__ counts,
                                                     int* __restrict__ tmp, int* __restrict__ btot) {
    __shared__ int wpre[16];
    int t = threadIdx.x, lane = t & 63, wid = t >> 6;
    int i = blockIdx.x * 1024 + t;
    int v = (i < NN) ? counts[i] : 0;
    int s = v;
    #pragma unroll
    for (int off = 1; off < 64; off <<= 1) {
        int u = __shfl_up(s, off, 64);
        if (lane >= off) s += u;
    }
    if (lane == 63) wpre[wid] = s;
    __syncthreads();
    if (t == 0) {
        int run = 0;
        #pragma unroll
        for (int j = 0; j < 16; ++j) { int xv = wpre[j]; wpre[j] = run; run += xv; }
        btot[blockIdx.x] = run;
    }
    __syncthreads();
    if (i < NN) tmp[i] = s + wpre[wid];
}

__global__ __launch_bounds__(64) void scanB_kernel(const int* __restrict__ btot,
                                                   int* __restrict__ boff, int nb) {
    int t = threadIdx.x;
    int v = (t < nb) ? btot[t] : 0;
    int s = v;
    #pragma unroll
    for (int off = 1; off < 64; off <<= 1) {
        int u = __shfl_up(s, off, 64);
        if (t >= off) s += u;
    }
    if (t < nb) boff[t] = s - v;   // exclusive
}

__global__ __launch_bounds__(1024) void scanC_kernel(const int* __restrict__ tmp,
                                                     const int* __restrict__ boff,
                                                     int* __restrict__ rowp) {
    int i = blockIdx.x * 1024 + threadIdx.x;
    if (i < NN) rowp[i + 1] = tmp[i] + boff[blockIdx.x];
    if (i == 0) rowp[0] = 0;
}

__global__ void fill2_kernel(const int* __restrict__ src, const int* __restrict__ dst,
                             const float* __restrict__ eattr, const int* __restrict__ rowp,
                             const int* __restrict__ rank, int2* __restrict__ rec) {
    int e = blockIdx.x * blockDim.x + threadIdx.x;
    if (e < NE) {
        int pos = rowp[dst[e]] + rank[e];
        rec[pos] = make_int2(src[e], __float_as_int(eattr[e]));   // one 8B scatter, no atomic
    }
}

// ------------- scatter-softmax aggregation v6: v5 structure + packed-fp16 message + 32b addressing -------------
// lanes 0..31 even edges, 32..63 odd edges; lane covers 4 channels (half4 8B gathers).
// msg computed in packed fp16 in the t*log2e-scaled domain: z = pk_fma(x2,tch2, pk_fma(a2,ewt2,ebt2)),
// relu via pk_max. exp/accumulate fp32; epilogue unscales by itc and re-adds softmax-invariant eps.
// Gather addresses 32-bit: soff = src<<7 pre-shuffle (max 5.12M, fits i32) -> SADDR+voffset loads.
__global__ __launch_bounds__(256) void agg_kernel(
    const _Float16* __restrict__ xh,
    const int* __restrict__ row_ptr,
    const int2* __restrict__ rec,
    const float* __restrict__ ew, const float* __restrict__ eb,
    const float* __restrict__ tptr, int layer,
    _Float16* __restrict__ oh)
{
    int d = blockIdx.x * 4 + (threadIdx.x >> 6);
    int lane = threadIdx.x & 63;
    int half = lane >> 5;
    int sl = lane & 31;
    int c0 = 4 * sl;
    float tc2 = tptr[layer] * 1.44269504f;   // t*log2e (t>0)
    float itc = 1.0f / tc2;
    _Float16 tch = (_Float16)tc2;
    h2 tch2; tch2.x = tch; tch2.y = tch;
    h2 ewt2[2], ebt2[2];
    #pragma unroll
    for (int k = 0; k < 2; ++k) {
        ewt2[k].x = (_Float16)(ew[c0 + 2*k]     * tc2);
        ewt2[k].y = (_Float16)(ew[c0 + 2*k + 1] * tc2);
        ebt2[k].x = (_Float16)(eb[c0 + 2*k]     * tc2);
        ebt2[k].y = (_Float16)(eb[c0 + 2*k + 1] * tc2);
    }
    int beg = row_ptr[d], end = row_ptr[d + 1];
    float den[4] = {0.f, 0.f, 0.f, 0.f}, num[4] = {0.f, 0.f, 0.f, 0.f};
    for (int base = beg; base < end; base += 64) {
        int cnt = min(64, end - base);
        int2 mv = rec[base + min(lane, cnt - 1)];   // 64 edges' meta, one coalesced 8B load
        int sv7 = mv.x << 7;                        // element offset of source row (32-bit safe)
        _Float16 avh = (_Float16)__int_as_float(mv.y);
        h2 avd; avd.x = avh; avd.y = avh;
        int avp = __builtin_bit_cast(int, avd);     // packed dup attr, shuffled as one word
        int pcnt = (cnt + 1) >> 1;                  // pairs of edges
        half4 gA[4], gB[4]; h2 aA[4], aB[4];
        auto issue = [&](half4 (&g)[4], h2 (&aa)[4], int p0) {
            #pragma unroll
            for (int u = 0; u < 4; ++u) {
                int je = 2 * (p0 + u) + half;
                int soff = __shfl(sv7, je, 64);
                int ap   = __shfl(avp, je, 64);
                aa[u] = __builtin_bit_cast(h2, ap);
                g[u] = *(const half4*)(xh + (unsigned)(soff + c0));
            }
        };
        auto consume = [&](half4 (&g)[4], h2 (&aa)[4], int p0) {
            #pragma unroll
            for (int u = 0; u < 4; ++u) {
                int je = 2 * (p0 + u) + half;
                if (je < cnt) {   // only tail pair diverges between halves
                    #pragma unroll
                    for (int k = 0; k < 2; ++k) {
                        h2 x2; x2.x = g[u][2*k]; x2.y = g[u][2*k + 1];
                        h2 z = aa[u] * ewt2[k] + ebt2[k];   // v_pk_fma_f16
                        z = x2 * tch2 + z;                  // v_pk_fma_f16 (x scaled into t-domain)
                        h2 zz; zz.x = (_Float16)0.f; zz.y = (_Float16)0.f;
                        z = __builtin_elementwise_max(z, zz);  // v_pk_max_f16 (relu)
                        float r0 = (float)z.x;
                        float r1 = (float)z.y;
                        float e0 = exp2f(r0), e1 = exp2f(r1);
                        den[2*k]     += e0; num[2*k]     = __fmaf_rn(e0, r0, num[2*k]);
                        den[2*k + 1] += e1; num[2*k + 1] = __fmaf_rn(e1, r1, num[2*k + 1]);
                    }
                }
            }
        };
        issue(gA, aA, 0);
        for (int p0 = 0; p0 < pcnt; p0 += 8) {
            if (p0 + 4 < pcnt) issue(gB, aB, p0 + 4);
            consume(gA, aA, p0);
            if (p0 + 8 < pcnt) issue(gA, aA, p0 + 8);
            if (p0 + 4 < pcnt) consume(gB, aB, p0 + 4);
        }
    }
    #pragma unroll
    for (int c = 0; c < 4; ++c) {
        den[c] += __shfl_xor(den[c], 32, 64);
        num[c] += __shfl_xor(num[c], 32, 64);
    }
    if (half == 0) {   // 32 lanes x 8B = full 256B row store
        half4 s4 = *(const half4*)(xh + ((size_t)d << 7) + c0);
        half4 ov;
        #pragma unroll
        for (int c = 0; c < 4; ++c) {
            float o = num[c] * itc / fmaxf(den[c], 1e-16f) + 1e-7f + (float)s4[c];
            ov[c] = (_Float16)o;
        }
        *(half4*)(oh + ((size_t)d << 7) + c0) = ov;
    }
}

// ------------- fp16 MFMA GEMM (node linear): A fp32 (converted while staging), Bt fp16 -------------
__global__ __launch_bounds__(256) void gemm_mfma(
    const float* __restrict__ A, const _Float16* __restrict__ Bt,
    const float* __restrict__ bias, _Float16* __restrict__ C,
    int M, int N, int K)
{
    constexpr int LDA = 40;
    __shared__ _Float16 As[64 * LDA];
    __shared__ _Float16 Bs[128 * LDA];
    int t = threadIdx.x;
    int row0 = blockIdx.y * 64;
    int col0 = blockIdx.x * 128;
    int w = t >> 6, lane = t & 63;
    int wm = w & 1, wn = w >> 1;
    int q = lane >> 4, l16 = lane & 15;
    f4 acc[2][4];
    #pragma unroll
    for (int i = 0; i < 2; ++i)
        #pragma unroll
        for (int j = 0; j < 4; ++j)
            acc[i][j] = (f4){0.f, 0.f, 0.f, 0.f};

    for (int k0 = 0; k0 < K; k0 += 32) {
        #pragma unroll
        for (int p = 0; p < 2; ++p) {   // A: 64 rows x 32 fp32 -> fp16 LDS
            int idx = t + p * 256;
            int r = idx >> 3, seg = idx & 7;
            float4 v = *(const float4*)(A + (size_t)(row0 + r) * K + k0 + seg * 4);
            half4 o; o.x = (_Float16)v.x; o.y = (_Float16)v.y; o.z = (_Float16)v.z; o.w = (_Float16)v.w;
            *(half4*)&As[r * LDA + seg * 4] = o;
        }
        #pragma unroll
        for (int i = 0; i < 2; ++i) {
            int idx = t + i * 256;
            int r = idx >> 2, seg = idx & 3;
            *(float4*)&Bs[r * LDA + seg * 8] =
                *(const float4*)(Bt + (size_t)(col0 + r) * K + k0 + seg * 8);
        }
        __syncthreads();
        half8 af[2], bf[4];
        #pragma unroll
        for (int i = 0; i < 2; ++i)
            af[i] = *(const half8*)&As[(wm * 32 + i * 16 + l16) * LDA + q * 8];
        #pragma unroll
        for (int j = 0; j < 4; ++j)
            bf[j] = *(const half8*)&Bs[(wn * 64 + j * 16 + l16) * LDA + q * 8];
        #pragma unroll
        for (int i = 0; i < 2; ++i)
            #pragma unroll
            for (int j = 0; j < 4; ++j)
                acc[i][j] = __builtin_amdgcn_mfma_f32_16x16x32_f16(af[i], bf[j], acc[i][j], 0, 0, 0);
        __syncthreads();
    }
    #pragma unroll
    for (int j = 0; j < 4; ++j) {
        int col = col0 + wn * 64 + j * 16 + l16;
        float bv = bias[col];
        #pragma unroll
        for (int i = 0; i < 2; ++i) {
            int rbase = row0 + wm * 32 + i * 16 + q * 4;
            #pragma unroll
            for (int rg = 0; rg < 4; ++rg)
                C[(size_t)(rbase + rg) * N + col] = (_Float16)(acc[i][j][rg] + bv);
        }
    }
}

// ------------- fused: lin1 -> LN1 -> ReLU -> lin2 (+bias) [+res] -> h; blockLN -> ReLU -> xout -------------
// Staged-LDS version (measured-best structure). FINAL=1: skip the dead h store.
template<int RES, int FINAL>
__global__ __launch_bounds__(256) void mlp_fused(
    const _Float16* __restrict__ Ain,
    const _Float16* __restrict__ w1t,
    const float* __restrict__ b1,
    const float* __restrict__ g1, const float* __restrict__ bt1,
    const _Float16* __restrict__ w2t,
    const float* __restrict__ b2,
    float* __restrict__ h,
    const float* __restrict__ bg, const float* __restrict__ bb,
    _Float16* __restrict__ xout)
{
    constexpr int LDA = 136;
    constexpr int LDB = 40;
    constexpr int LDM = 264;
    __shared__ _Float16 As[64 * LDA];
    __shared__ _Float16 Bs[256 * LDB];
    __shared__ _Float16 midh[64 * LDM];
    __shared__ float ssum[64][2], ssum2[64][2];
    int t = threadIdx.x;
    int row0 = blockIdx.x * 64;
    int w = t >> 6, lane = t & 63;
    int wm = w & 1, wn = w >> 1;
    int q = lane >> 4, l16 = lane & 15;

    #pragma unroll
    for (int p = 0; p < 4; ++p) {
        int idx = t + p * 256;
        int r = idx >> 4, seg = idx & 15;
        *(float4*)&As[r * LDA + seg * 8] =
            *(const float4*)(Ain + (size_t)(row0 + r) * 128 + seg * 8);
    }

    f4 acc[2][8];
    #pragma unroll
    for (int i = 0; i < 2; ++i)
        #pragma unroll
        for (int j = 0; j < 8; ++j)
            acc[i][j] = (f4){0.f, 0.f, 0.f, 0.f};
    for (int k0 = 0; k0 < 128; k0 += 32) {
        #pragma unroll
        for (int p = 0; p < 4; ++p) {
            int idx = t + p * 256;
            int r = idx >> 2, seg = idx & 3;
            *(float4*)&Bs[r * LDB + seg * 8] =
                *(const float4*)(w1t + (size_t)r * 128 + k0 + seg * 8);
        }
        __syncthreads();
        half8 af[2], bf[8];
        #pragma unroll
        for (int i = 0; i < 2; ++i)
            af[i] = *(const half8*)&As[(wm * 32 + i * 16 + l16) * LDA + k0 + q * 8];
        #pragma unroll
        for (int j = 0; j < 8; ++j)
            bf[j] = *(const half8*)&Bs[(wn * 128 + j * 16 + l16) * LDB + q * 8];
        #pragma unroll
        for (int i = 0; i < 2; ++i)
            #pragma unroll
            for (int j = 0; j < 8; ++j)
                acc[i][j] = __builtin_amdgcn_mfma_f32_16x16x32_f16(af[i], bf[j], acc[i][j], 0, 0, 0);
        __syncthreads();
    }

    float b1v[8], g1v[8], bt1v[8];
    #pragma unroll
    for (int j = 0; j < 8; ++j) {
        int col = wn * 128 + j * 16 + l16;
        b1v[j] = b1[col]; g1v[j] = g1[col]; bt1v[j] = bt1[col];
    }
    float vals[2][8][4];
    #pragma unroll
    for (int i = 0; i < 2; ++i)
        #pragma unroll
        for (int j = 0; j < 8; ++j)
            #pragma unroll
            for (int rg = 0; rg < 4; ++rg)
                vals[i][j][rg] = acc[i][j][rg] + b1v[j];
    #pragma unroll
    for (int i = 0; i < 2; ++i) {
        #pragma unroll
        for (int rg = 0; rg < 4; ++rg) {
            float ps = 0.f, ps2 = 0.f;
            #pragma unroll
            for (int j = 0; j < 8; ++j) { float v = vals[i][j][rg]; ps += v; ps2 += v * v; }
            #pragma unroll
            for (int off = 1; off < 16; off <<= 1) {
                ps  += __shfl_xor(ps,  off, 16);
                ps2 += __shfl_xor(ps2, off, 16);
            }
            if (l16 == 0) {
                int row = wm * 32 + i * 16 + q * 4 + rg;
                ssum[row][wn] = ps; ssum2[row][wn] = ps2;
            }
        }
    }
    __syncthreads();
    #pragma unroll
    for (int i = 0; i < 2; ++i) {
        #pragma unroll
        for (int rg = 0; rg < 4; ++rg) {
            int row = wm * 32 + i * 16 + q * 4 + rg;
            float S = ssum[row][0] + ssum[row][1];
            float S2 = ssum2[row][0] + ssum2[row][1];
            float mu = S * (1.0f / 256.0f);
            float var = S2 * (1.0f / 256.0f) - mu * mu;
            float rstd = rsqrtf(var + 1e-5f);
            #pragma unroll
            for (int j = 0; j < 8; ++j) {
                int col = wn * 128 + j * 16 + l16;
                float o = fmaxf((vals[i][j][rg] - mu) * rstd * g1v[j] + bt1v[j], 0.f);
                midh[row * LDM + col] = (_Float16)o;
            }
        }
    }
    __syncthreads();

    f4 acc2[2][4];
    #pragma unroll
    for (int i = 0; i < 2; ++i)
        #pragma unroll
        for (int j = 0; j < 4; ++j)
            acc2[i][j] = (f4){0.f, 0.f, 0.f, 0.f};
    for (int k0 = 0; k0 < 256; k0 += 32) {
        #pragma unroll
        for (int p = 0; p < 2; ++p) {
            int idx = t + p * 256;
            int r = idx >> 2, seg = idx & 3;
            *(float4*)&Bs[r * LDB + seg * 8] =
                *(const float4*)(w2t + (size_t)r * 256 + k0 + seg * 8);
        }
        __syncthreads();
        half8 af2[2], bf2[4];
        #pragma unroll
        for (int i = 0; i < 2; ++i)
            af2[i] = *(const half8*)&midh[(wm * 32 + i * 16 + l16) * LDM + k0 + q * 8];
        #pragma unroll
        for (int j = 0; j < 4; ++j)
            bf2[j] = *(const half8*)&Bs[(wn * 64 + j * 16 + l16) * LDB + q * 8];
        #pragma unroll
        for (int i = 0; i < 2; ++i)
            #pragma unroll
            for (int j = 0; j < 4; ++j)
                acc2[i][j] = __builtin_amdgcn_mfma_f32_16x16x32_f16(af2[i], bf2[j], acc2[i][j], 0, 0, 0);
        __syncthreads();
    }

    float b2v[4], bgv[4], bbv[4];
    #pragma unroll
    for (int j = 0; j < 4; ++j) {
        int col = wn * 64 + j * 16 + l16;
        b2v[j] = b2[col]; bgv[j] = bg[col]; bbv[j] = bb[col];
    }
    float ov[2][4][4];
    #pragma unroll
    for (int i = 0; i < 2; ++i) {
        #pragma unroll
        for (int rg = 0; rg < 4; ++rg) {
            int row = wm * 32 + i * 16 + q * 4 + rg;
            #pragma unroll
            for (int j = 0; j < 4; ++j) {
                int col = wn * 64 + j * 16 + l16;
                float v = acc2[i][j][rg] + b2v[j];
                size_t gidx = (size_t)(row0 + row) * 128 + col;
                if (RES) v += h[gidx];
                if (!FINAL) h[gidx] = v;   // dead after last layer
                ov[i][j][rg] = v;
            }
        }
    }
    #pragma unroll
    for (int i = 0; i < 2; ++i) {
        #pragma unroll
        for (int rg = 0; rg < 4; ++rg) {
            float ps = 0.f, ps2 = 0.f;
            #pragma unroll
            for (int j = 0; j < 4; ++j) { float v = ov[i][j][rg]; ps += v; ps2 += v * v; }
            #pragma unroll
            for (int off = 1; off < 16; off <<= 1) {
                ps  += __shfl_xor(ps,  off, 16);
                ps2 += __shfl_xor(ps2, off, 16);
            }
            if (l16 == 0) {
                int row = wm * 32 + i * 16 + q * 4 + rg;
                ssum[row][wn] = ps; ssum2[row][wn] = ps2;
            }
        }
    }
    __syncthreads();
    #pragma unroll
    for (int i = 0; i < 2; ++i) {
        #pragma unroll
        for (int rg = 0; rg < 4; ++rg) {
            int row = wm * 32 + i * 16 + q * 4 + rg;
            float S = ssum[row][0] + ssum[row][1];
            float S2 = ssum2[row][0] + ssum2[row][1];
            float mu = S * (1.0f / 128.0f);
            float var = S2 * (1.0f / 128.0f) - mu * mu;
            float rstd = rsqrtf(var + 1e-5f);
            #pragma unroll
            for (int j = 0; j < 4; ++j) {
                int col = wn * 64 + j * 16 + l16;
                float o = fmaxf((ov[i][j][rg] - mu) * rstd * bgv[j] + bbv[j], 0.f);
                xout[(size_t)(row0 + row) * 128 + col] = (_Float16)o;
            }
        }
    }
}

// ------------- mean pool over sorted batch (half input): local accumulate, few atomics -------------
__global__ __launch_bounds__(128) void pool_kernel(
    const _Float16* __restrict__ f, const int* __restrict__ batch, float* __restrict__ pooled)
{
    int g = blockIdx.x;
    int chunk = blockIdx.y;
    int c = threadIdx.x;
    int s = lower_bound_dev(batch, NN, g);
    int e = lower_bound_dev(batch, NN, g + 1);
    int len = e - s;
    if (len <= 0) return;
    int nch = gridDim.y;
    int per = (len + nch - 1) / nch;
    int cs = s + chunk * per;
    int ce = min(cs + per, e);
    if (cs >= ce) return;
    float acc = 0.f;
    for (int n = cs; n < ce; ++n) acc += (float)f[(size_t)n * HH + c];
    atomicAdd(&pooled[g * HH + c], acc);
}

// ------------- MLP head (pooled holds per-graph sums; divide by count here) -------------
__global__ __launch_bounds__(128) void head_kernel(
    const float* __restrict__ pooled, const int* __restrict__ batch,
    const float* __restrict__ hw1, const float* __restrict__ hb1,
    const float* __restrict__ hw2, const float* __restrict__ hb2,
    const float* __restrict__ hw3, const float* __restrict__ hb3,
    float* __restrict__ out)
{
    __shared__ float p[HH];
    __shared__ float o1[64];
    __shared__ float o2[32];
    int g = blockIdx.x;
    int t = threadIdx.x;
    int s = lower_bound_dev(batch, NN, g);
    int e = lower_bound_dev(batch, NN, g + 1);
    float cnt = fmaxf((float)(e - s), 1.0f);
    p[t] = pooled[g * HH + t] / cnt;
    __syncthreads();
    if (t < 64) {
        float acc = hb1[t];
        for (int k = 0; k < HH; ++k) acc += p[k] * hw1[k * 64 + t];
        o1[t] = fmaxf(acc, 0.f);
    }
    __syncthreads();
    if (t < 32) {
        float acc = hb2[t];
        for (int k = 0; k < 64; ++k) acc += o1[k] * hw2[k * 32 + t];
        o2[t] = fmaxf(acc, 0.f);
    }
    __syncthreads();
    if (t == 0) {
        float acc = hb3[0];
        for (int k = 0; k < 32; ++k) acc += o2[k] * hw3[k];
        out[g] = acc;
    }
}

extern "C" void kernel_launch(void* const* d_in, const int* in_sizes, int n_in,
                              void* d_out, int out_size, void* d_ws, size_t ws_size,
                              hipStream_t stream)
{
    const float* x      = (const float*)d_in[0];
    const float* eattr  = (const float*)d_in[1];
    const float* node_w = (const float*)d_in[2];
    const float* node_b = (const float*)d_in[3];
    const float* edge_w = (const float*)d_in[4];
    const float* edge_b = (const float*)d_in[5];
    const float* tptr   = (const float*)d_in[6];
    const float* lin1_w = (const float*)d_in[7];
    const float* lin1_b = (const float*)d_in[8];
    const float* ln1_g  = (const float*)d_in[9];
    const float* ln1_bt = (const float*)d_in[10];
    const float* lin2_w = (const float*)d_in[11];
    const float* lin2_b = (const float*)d_in[12];
    const float* blk_g  = (const float*)d_in[13];
    const float* blk_b  = (const float*)d_in[14];
    const float* hw1    = (const float*)d_in[15];
    const float* hb1    = (const float*)d_in[16];
    const float* hw2    = (const float*)d_in[17];
    const float* hb2    = (const float*)d_in[18];
    const float* hw3    = (const float*)d_in[19];
    const float* hb3    = (const float*)d_in[20];
    const int*   eidx   = (const int*)d_in[21];
    const int*   batch  = (const int*)d_in[22];
    const int* src = eidx;
    const int* dst = eidx + NE;
    float* out = (float*)d_out;

    char* ws = (char*)d_ws;
    size_t off = 0;
    auto carve = [&](size_t bytes) -> char* {
        char* p = ws + off;
        off = (off + bytes + 255) & ~(size_t)255;
        return p;
    };
    float*    h      = (float*)carve((size_t)NN * HH * 4);
    _Float16* xnh    = (_Float16*)carve((size_t)NN * HH * 2);
    _Float16* oh     = (_Float16*)carve((size_t)NN * HH * 2);
    _Float16* rh     = (_Float16*)carve((size_t)NN * HH * 2);
    _Float16* nwt    = (_Float16*)carve((size_t)16384 * 2);
    _Float16* w1t    = (_Float16*)carve((size_t)98304 * 2);
    _Float16* w2t    = (_Float16*)carve((size_t)98304 * 2);
    int*      counts = (int*)carve((size_t)NN * 4);
    int*      rank   = (int*)carve((size_t)NE * 4);
    int*      tmp    = (int*)carve((size_t)NN * 4);
    int*      btot   = (int*)carve((size_t)64 * 4);
    int*      boff   = (int*)carve((size_t)64 * 4);
    int*      rowp   = (int*)carve((size_t)(NN + 1) * 4);
    int2*     rec    = (int2*)carve((size_t)NE * 8);
    float*    pooled = (float*)carve((size_t)NG * HH * 4);

    hipMemsetAsync(counts, 0, (size_t)NN * 4, stream);
    hipMemsetAsync(pooled, 0, (size_t)NG * HH * 4, stream);

    {
        int total = 16384 + 98304 + 98304;   // 832 blocks
        convert_w_kernel<<<(total + 255) / 256, 256, 0, stream>>>(
            node_w, lin1_w, lin2_w, nwt, w1t, w2t);
    }
    const int NB = (NN + 1023) / 1024;   // 40
    count_rank_kernel<<<(NE + 255) / 256, 256, 0, stream>>>(dst, counts, rank);
    scanA_kernel<<<NB, 1024, 0, stream>>>(counts, tmp, btot);
    scanB_kernel<<<1, 64, 0, stream>>>(btot, boff, NB);
    scanC_kernel<<<NB, 1024, 0, stream>>>(tmp, boff, rowp);
    fill2_kernel<<<(NE + 255) / 256, 256, 0, stream>>>(src, dst, eattr, rowp, rank, rec);

    // node linear: xnh = half(x @ node_w + node_b)  (reads fp32 x directly)
    gemm_mfma<<<dim3(1, NN / 64), 256, 0, stream>>>(x, nwt, node_b, xnh, NN, HH, DIM_IN);

    // layer 0 (no residual; post-LN uses blk[1])
    agg_kernel<<<NN / 4, 256, 0, stream>>>(xnh, rowp, rec, edge_w, edge_b, tptr, 0, oh);
    mlp_fused<0, 0><<<NN / 64, 256, 0, stream>>>(
        oh, w1t, lin1_b, ln1_g, ln1_bt, w2t, lin2_b,
        h, blk_g + 1 * HH, blk_b + 1 * HH, xnh);
    // layer 1 (residual; post-LN uses blk[2])
    agg_kernel<<<NN / 4, 256, 0, stream>>>(xnh, rowp, rec, edge_w, edge_b, tptr, 1, oh);
    mlp_fused<1, 0><<<NN / 64, 256, 0, stream>>>(
        oh, w1t + 32768, lin1_b + HH2, ln1_g + HH2, ln1_bt + HH2, w2t + 32768, lin2_b + HH,
        h, blk_g + 2 * HH, blk_b + 2 * HH, xnh);
    // layer 2 (residual; final LN uses blk[0] -> rh; dead h store skipped)
    agg_kernel<<<NN / 4, 256, 0, stream>>>(xnh, rowp, rec, edge_w, edge_b, tptr, 2, oh);
    mlp_fused<1, 1><<<NN / 64, 256, 0, stream>>>(
        oh, w1t + 2 * 32768, lin1_b + 2 * HH2, ln1_g + 2 * HH2, ln1_bt + 2 * HH2,
        w2t + 2 * 32768, lin2_b + 2 * HH,
        h, blk_g, blk_b, rh);

    pool_kernel<<<dim3(NG, 8), 128, 0, stream>>>(rh, batch, pooled);
    head_kernel<<<NG, 128, 0, stream>>>(pooled, batch, hw1, hb1, hw2, hb2, hw3, hb3, out);
}